// Round 10
// baseline (488.363 us; speedup 1.0000x reference)
//
#include <hip/hip_runtime.h>
#include <hip/hip_fp16.h>

#define N_NODES   100000
#define N_EDGES   3200000
#define IN_CH     128
#define NUM_GRAPHS 1000
#define NHALF     50000    // src-half boundary
#define NBH       391      // dst-buckets per src-half (256 nodes each)
#define NB2       782      // total buckets = 2 src-halves x 391
#define CAPB      4608     // per-bucket window capacity (mean 4096, +8 sigma)
#define CHUNK     4096     // edges per block in the binning pass
#define NBLK_BIN  782      // ceil(3200000/4096)
#define RPW       257      // rowptr words per bucket (256 nodes + sentinel)

typedef __attribute__((ext_vector_type(8))) _Float16 half8;
typedef __attribute__((ext_vector_type(4))) float    float4v;

// ---------------------------------------------------------------------------
// cursor[b] = b * CAPB  (fixed-capacity strided windows -> no count/scan pass)
// ---------------------------------------------------------------------------
__global__ __launch_bounds__(1024) void k_init_cursor(int* __restrict__ cursor)
{
    int i = threadIdx.x;
    if (i < NB2) cursor[i] = i * CAPB;
}

// ---------------------------------------------------------------------------
// Scatter: LDS counting sort per 4096-edge chunk, then linear write-out into
// per-bucket windows. bucket = (src>=50000)*391 + (dst>>8);
// payload = src | (dst&255)<<17.  sbk[slot] records the bucket id during
// placement so the write-out is a direct lookup (replaces R7's ~10-deep
// dependent-LDS binary search — the serial critical path of this kernel).
// Output is bit-identical to R7's.
// ---------------------------------------------------------------------------
__global__ __launch_bounds__(256) void k_scatter_pairs(const int* __restrict__ ei,
                                                       int* __restrict__ cursor,
                                                       int* __restrict__ pairbuf)
{
    __shared__ int h[NB2];          // counts, then local cursor
    __shared__ int gbase[NB2];
    __shared__ int sstart[NB2 + 1]; // local exclusive scan
    __shared__ int sa[1024];
    __shared__ int sb[1024];
    __shared__ int ebuf[CHUNK];
    __shared__ unsigned short sbk[CHUNK];
    int tid = threadIdx.x;
    for (int i = tid; i < NB2; i += 256) h[i] = 0;
    __syncthreads();
    int base = blockIdx.x * CHUNK;
    int end = min(base + CHUNK, N_EDGES);
    int cntE = end - base;
    for (int e = base + tid; e < end; e += 256) {
        int src = ei[e];
        int dst = ei[N_EDGES + e];
        int b = ((src >= NHALF) ? NBH : 0) + (dst >> 8);
        atomicAdd(&h[b], 1);
    }
    __syncthreads();
    // inclusive Hillis-Steele scan over 1024 (padded), 256 threads x 4
#pragma unroll
    for (int r = 0; r < 4; ++r) {
        int i = tid + 256 * r;
        sa[i] = (i < NB2) ? h[i] : 0;
    }
    __syncthreads();
    int* A = sa; int* B = sb;
    for (int off = 1; off < 1024; off <<= 1) {
        int v[4];
#pragma unroll
        for (int r = 0; r < 4; ++r) {
            int i = tid + 256 * r;
            v[r] = A[i] + ((i >= off) ? A[i - off] : 0);
        }
        __syncthreads();
#pragma unroll
        for (int r = 0; r < 4; ++r) B[tid + 256 * r] = v[r];
        __syncthreads();
        int* tmp = A; A = B; B = tmp;
    }
    if (tid == 0) sstart[0] = 0;
    for (int i = tid; i < NB2; i += 256) sstart[i + 1] = A[i];
    __syncthreads();
    // reserve global windows; reset h as local cursor
    for (int i = tid; i < NB2; i += 256) {
        int c = sstart[i + 1] - sstart[i];
        gbase[i] = c ? atomicAdd(&cursor[i], c) : 0;
        h[i] = 0;
    }
    __syncthreads();
    // place edges bucket-sorted into ebuf; record bucket id per slot
    for (int e = base + tid; e < end; e += 256) {
        int src = ei[e];
        int dst = ei[N_EDGES + e];
        int b = ((src >= NHALF) ? NBH : 0) + (dst >> 8);
        int off = atomicAdd(&h[b], 1);
        int slot = sstart[b] + off;
        ebuf[slot] = src | ((dst & 255) << 17);
        sbk[slot] = (unsigned short)b;
    }
    __syncthreads();
    // linear write-out, direct bucket lookup (no binary search)
    for (int i = tid; i < cntE; i += 256) {
        int b = sbk[i];
        pairbuf[gbase[b] + (i - sstart[b])] = ebuf[i];
    }
}

// ---------------------------------------------------------------------------
// Build CSR: one block per bucket window. LDS histogram over 256 local dst,
// scan -> rowptr[b*257 + i] (+ sentinel), scatter src ids into the bucket's
// contiguous csr window.
// ---------------------------------------------------------------------------
__global__ __launch_bounds__(256) void k_build_csr(const int* __restrict__ cursor,
                                                   const int* __restrict__ pairbuf,
                                                   int* __restrict__ rowptr,
                                                   int* __restrict__ csr)
{
    __shared__ int cnt[256];
    __shared__ int scanv[256];
    __shared__ int ebuf[CAPB];
    int b = blockIdx.x;
    int base = b * CAPB;
    int cntE = cursor[b] - base;
    int tid = threadIdx.x;
    cnt[tid] = 0;
    __syncthreads();
    for (int i = tid; i < cntE; i += 256) {
        int p = pairbuf[base + i];
        ebuf[i] = p;
        atomicAdd(&cnt[(p >> 17) & 255], 1);
    }
    __syncthreads();
    int v = cnt[tid];
    scanv[tid] = v;
    __syncthreads();
    for (int off = 1; off < 256; off <<= 1) {
        int t = (tid >= off) ? scanv[tid - off] : 0;
        __syncthreads();
        scanv[tid] += t;
        __syncthreads();
    }
    int ex = scanv[tid] - v;           // exclusive within bucket
    rowptr[b * RPW + tid] = base + ex;
    if (tid == 0) rowptr[b * RPW + 256] = base + cntE;
    __syncthreads();
    cnt[tid] = ex;                     // local cursor
    __syncthreads();
    for (int i = tid; i < cntE; i += 256) {
        int p = ebuf[i];
        int pos = atomicAdd(&cnt[(p >> 17) & 255], 1);
        csr[base + pos] = p & 0x1FFFF;
    }
}

// ---------------------------------------------------------------------------
// transform1 via MFMA f16: t1 = half(x @ W1_nbr); r1 = x @ W1_root + b1.
// ---------------------------------------------------------------------------
__global__ __launch_bounds__(256) void k_transform1_mfma(
    const float* __restrict__ x,
    const float* __restrict__ W1n, const float* __restrict__ W1r,
    const float* __restrict__ b1,
    __half* __restrict__ t1, float* __restrict__ r1)
{
    int wave = threadIdx.x >> 6;
    int lane = threadIdx.x & 63;
    int tile = blockIdx.x * 4 + wave;
    int node0 = tile * 16;
    int m = lane & 15, quad = lane >> 4;
    int row = node0 + m;
    if (row >= N_NODES) row = N_NODES - 1;     // clamp (stores are guarded)
    const float* xr = x + (size_t)row * IN_CH + quad * 8;

    float4v acc_n = {0.f, 0.f, 0.f, 0.f};
    float4v acc_r = {0.f, 0.f, 0.f, 0.f};
#pragma unroll
    for (int kc = 0; kc < 4; ++kc) {
        half8 a, bn, br;
        const float* xp = xr + kc * 32;
#pragma unroll
        for (int j = 0; j < 8; ++j) a[j] = (_Float16)xp[j];
        int kbase = kc * 32 + quad * 8;
#pragma unroll
        for (int j = 0; j < 8; ++j) {
            bn[j] = (_Float16)W1n[(kbase + j) * 16 + m];
            br[j] = (_Float16)W1r[(kbase + j) * 16 + m];
        }
        acc_n = __builtin_amdgcn_mfma_f32_16x16x32_f16(a, bn, acc_n, 0, 0, 0);
        acc_r = __builtin_amdgcn_mfma_f32_16x16x32_f16(a, br, acc_r, 0, 0, 0);
    }
    float bias = b1[m];
#pragma unroll
    for (int reg = 0; reg < 4; ++reg) {
        int node = node0 + quad * 4 + reg;
        if (node < N_NODES) {
            t1[node * 16 + m] = __float2half_rn(acc_n[reg]);
            r1[node * 16 + m] = acc_r[reg] + bias;
        }
    }
}

// ---------------------------------------------------------------------------
// Layer-1 gather: 16 channels, both src-halves in one pass (t1 = 3.2 MB,
// L2-resident). 8 lanes/node (half2), 8-deep unroll. Register accumulate.
// (R7 verbatim — known good.)
// ---------------------------------------------------------------------------
__global__ __launch_bounds__(256) void k_gather16b(
    const int* __restrict__ rowptr, const int* __restrict__ csr,
    const __half2* __restrict__ t, float* __restrict__ agg)
{
    int tid = blockIdx.x * 256 + threadIdx.x;      // exactly N_NODES*8
    int n = tid >> 3, cp = tid & 7;
    float2 a0 = {0.f,0.f}, a1 = {0.f,0.f}, a2 = {0.f,0.f}, a3 = {0.f,0.f};
#pragma unroll
    for (int hh = 0; hh < 2; ++hh) {
        int idx = (hh * NBH + (n >> 8)) * RPW + (n & 255);
        int j = rowptr[idx], end = rowptr[idx + 1];
        for (; j + 7 < end; j += 8) {
            int s0 = __builtin_nontemporal_load(&csr[j]);
            int s1 = __builtin_nontemporal_load(&csr[j + 1]);
            int s2 = __builtin_nontemporal_load(&csr[j + 2]);
            int s3 = __builtin_nontemporal_load(&csr[j + 3]);
            int s4 = __builtin_nontemporal_load(&csr[j + 4]);
            int s5 = __builtin_nontemporal_load(&csr[j + 5]);
            int s6 = __builtin_nontemporal_load(&csr[j + 6]);
            int s7 = __builtin_nontemporal_load(&csr[j + 7]);
            float2 f0 = __half22float2(t[s0 * 8 + cp]);
            float2 f1 = __half22float2(t[s1 * 8 + cp]);
            float2 f2 = __half22float2(t[s2 * 8 + cp]);
            float2 f3 = __half22float2(t[s3 * 8 + cp]);
            float2 f4 = __half22float2(t[s4 * 8 + cp]);
            float2 f5 = __half22float2(t[s5 * 8 + cp]);
            float2 f6 = __half22float2(t[s6 * 8 + cp]);
            float2 f7 = __half22float2(t[s7 * 8 + cp]);
            a0.x += f0.x; a0.y += f0.y;  a1.x += f1.x; a1.y += f1.y;
            a2.x += f2.x; a2.y += f2.y;  a3.x += f3.x; a3.y += f3.y;
            a0.x += f4.x; a0.y += f4.y;  a1.x += f5.x; a1.y += f5.y;
            a2.x += f6.x; a2.y += f6.y;  a3.x += f7.x; a3.y += f7.y;
        }
        for (; j < end; ++j) {
            float2 f = __half22float2(t[__builtin_nontemporal_load(&csr[j]) * 8 + cp]);
            a0.x += f.x; a0.y += f.y;
        }
    }
    float rx = (a0.x + a1.x) + (a2.x + a3.x);
    float ry = (a0.y + a1.y) + (a2.y + a3.y);
    __builtin_nontemporal_store(rx, &agg[n * 16 + 2 * cp]);
    __builtin_nontemporal_store(ry, &agg[n * 16 + 2 * cp + 1]);
}

// ---------------------------------------------------------------------------
// Layer-2/3 gather: 32 channels, ONE src-half per launch (random reads
// confined to a 3.2 MB table half -> per-XCD L2 resident). 16 lanes/node.
// bbase = 0 (half A, overwrite agg) or NBH (half B, accumulate).
// (R7 verbatim — known good.)
// ---------------------------------------------------------------------------
__global__ __launch_bounds__(256) void k_gather32h(
    const int* __restrict__ rowptr, const int* __restrict__ csr,
    const __half2* __restrict__ t, float* __restrict__ agg,
    int bbase, int accflag)
{
    int tid = blockIdx.x * 256 + threadIdx.x;      // exactly N_NODES*16
    int n = tid >> 4, cp = tid & 15;
    int idx = (bbase + (n >> 8)) * RPW + (n & 255);
    int j = rowptr[idx], end = rowptr[idx + 1];
    float2 a0 = {0.f,0.f}, a1 = {0.f,0.f}, a2 = {0.f,0.f}, a3 = {0.f,0.f};
    for (; j + 7 < end; j += 8) {
        int s0 = __builtin_nontemporal_load(&csr[j]);
        int s1 = __builtin_nontemporal_load(&csr[j + 1]);
        int s2 = __builtin_nontemporal_load(&csr[j + 2]);
        int s3 = __builtin_nontemporal_load(&csr[j + 3]);
        int s4 = __builtin_nontemporal_load(&csr[j + 4]);
        int s5 = __builtin_nontemporal_load(&csr[j + 5]);
        int s6 = __builtin_nontemporal_load(&csr[j + 6]);
        int s7 = __builtin_nontemporal_load(&csr[j + 7]);
        float2 f0 = __half22float2(t[s0 * 16 + cp]);
        float2 f1 = __half22float2(t[s1 * 16 + cp]);
        float2 f2 = __half22float2(t[s2 * 16 + cp]);
        float2 f3 = __half22float2(t[s3 * 16 + cp]);
        float2 f4 = __half22float2(t[s4 * 16 + cp]);
        float2 f5 = __half22float2(t[s5 * 16 + cp]);
        float2 f6 = __half22float2(t[s6 * 16 + cp]);
        float2 f7 = __half22float2(t[s7 * 16 + cp]);
        a0.x += f0.x; a0.y += f0.y;  a1.x += f1.x; a1.y += f1.y;
        a2.x += f2.x; a2.y += f2.y;  a3.x += f3.x; a3.y += f3.y;
        a0.x += f4.x; a0.y += f4.y;  a1.x += f5.x; a1.y += f5.y;
        a2.x += f6.x; a2.y += f6.y;  a3.x += f7.x; a3.y += f7.y;
    }
    for (; j < end; ++j) {
        float2 f = __half22float2(t[__builtin_nontemporal_load(&csr[j]) * 16 + cp]);
        a0.x += f.x; a0.y += f.y;
    }
    float rx = (a0.x + a1.x) + (a2.x + a3.x);
    float ry = (a0.y + a1.y) + (a2.y + a3.y);
    if (accflag) {
        rx += __builtin_nontemporal_load(&agg[n * 32 + 2 * cp]);
        ry += __builtin_nontemporal_load(&agg[n * 32 + 2 * cp + 1]);
    }
    __builtin_nontemporal_store(rx, &agg[n * 32 + 2 * cp]);
    __builtin_nontemporal_store(ry, &agg[n * 32 + 2 * cp + 1]);
}

// ---------------------------------------------------------------------------
// K3: h1 = relu(r1 + agg16); t2 = half(h1 @ W2_nbr); r2 = h1 @ W2_root + b2
// ---------------------------------------------------------------------------
__global__ __launch_bounds__(256) void k_combine1_transform2(
    const float* __restrict__ r1, const float* __restrict__ agg1,
    const float* __restrict__ W2n, const float* __restrict__ W2r,
    const float* __restrict__ b2,
    __half* __restrict__ t2, float* __restrict__ r2)
{
    __shared__ float sW[16 * 64];   // [k][c]
    __shared__ float sh[4 * 16];

    for (int i = threadIdx.x; i < 16 * 64; i += 256) {
        int k = i >> 6, c = i & 63;
        sW[i] = (c < 32) ? W2n[k * 32 + c] : W2r[k * 32 + (c - 32)];
    }
    int node0 = blockIdx.x * 4;
    if (threadIdx.x < 64) {
        int idx = node0 * 16 + threadIdx.x;
        float v = r1[idx] + agg1[idx];
        sh[threadIdx.x] = v > 0.f ? v : 0.f;
    }
    __syncthreads();

    int c  = threadIdx.x & 63;
    int nl = threadIdx.x >> 6;
    const float* hr = &sh[nl * 16];
    float acc = 0.f;
#pragma unroll
    for (int k = 0; k < 16; ++k) acc += hr[k] * sW[k * 64 + c];

    int node = node0 + nl;
    if (c < 32) t2[node * 32 + c] = __float2half_rn(acc);
    else        r2[node * 32 + (c - 32)] = acc + b2[c - 32];
}

// ---------------------------------------------------------------------------
// K5: h2 = relu(r2 + agg32); t3 = half(h2 @ W3_nbr); r3 = h2 @ W3_root + b3
// t3/r3 alias t2/r2 — block reads its slice to LDS, barrier, overwrites.
// ---------------------------------------------------------------------------
__global__ __launch_bounds__(256) void k_combine2_transform3(
    const float* __restrict__ r2, const float* __restrict__ agg2,
    const float* __restrict__ W3n, const float* __restrict__ W3r,
    const float* __restrict__ b3,
    __half* __restrict__ t3, float* __restrict__ r3)
{
    __shared__ float sW[32 * 64];
    __shared__ float sh[4 * 32];

    for (int i = threadIdx.x; i < 32 * 64; i += 256) {
        int k = i >> 6, c = i & 63;
        sW[i] = (c < 32) ? W3n[k * 32 + c] : W3r[k * 32 + (c - 32)];
    }
    int node0 = blockIdx.x * 4;
    if (threadIdx.x < 128) {
        int idx = node0 * 32 + threadIdx.x;
        float v = r2[idx] + agg2[idx];
        sh[threadIdx.x] = v > 0.f ? v : 0.f;
    }
    __syncthreads();

    int c  = threadIdx.x & 63;
    int nl = threadIdx.x >> 6;
    const float* hr = &sh[nl * 32];
    float acc = 0.f;
#pragma unroll
    for (int k = 0; k < 32; ++k) acc += hr[k] * sW[k * 64 + c];

    int node = node0 + nl;
    if (c < 32) t3[node * 32 + c] = __float2half_rn(acc);
    else        r3[node * 32 + (c - 32)] = acc + b3[c - 32];
}

// ---------------------------------------------------------------------------
// K7: h3 = relu(r3 + agg32); pooled[batch[n]] += h3[n]
// ---------------------------------------------------------------------------
__global__ __launch_bounds__(256) void k_combine3_pool(
    const float* __restrict__ r3, const float* __restrict__ agg3,
    const int* __restrict__ batch, float* __restrict__ pooled)
{
    int tid = blockIdx.x * 256 + threadIdx.x;
    if (tid >= N_NODES * 32) return;
    int n = tid >> 5, c = tid & 31;
    float v = r3[tid] + agg3[tid];
    v = v > 0.f ? v : 0.f;
    atomicAdd(&pooled[batch[n] * 32 + c], v);
}

// ---------------------------------------------------------------------------
// K8: out = pooled @ Wlin + blin   (1000x32 @ 32x64)
// ---------------------------------------------------------------------------
__global__ __launch_bounds__(64) void k_final(
    const float* __restrict__ pooled, const float* __restrict__ Wlin,
    const float* __restrict__ blin, float* __restrict__ out)
{
    int g = blockIdx.x;
    int o = threadIdx.x;
    float acc = blin[o];
#pragma unroll
    for (int k = 0; k < 32; ++k) acc += pooled[g * 32 + k] * Wlin[k * 64 + o];
    out[g * 64 + o] = acc;
}

static inline char* align16p(char* p) {
    return (char*)(((uintptr_t)p + 15) & ~(uintptr_t)15);
}

extern "C" void kernel_launch(void* const* d_in, const int* in_sizes, int n_in,
                              void* d_out, int out_size, void* d_ws, size_t ws_size,
                              hipStream_t stream) {
    const float* x     = (const float*)d_in[0];
    const int*   ei    = (const int*)d_in[1];
    const int*   batch = (const int*)d_in[2];
    const float* W1r   = (const float*)d_in[3];
    const float* W1n   = (const float*)d_in[4];
    const float* b1    = (const float*)d_in[5];
    const float* W2r   = (const float*)d_in[6];
    const float* W2n   = (const float*)d_in[7];
    const float* b2    = (const float*)d_in[8];
    const float* W3r   = (const float*)d_in[9];
    const float* W3n   = (const float*)d_in[10];
    const float* b3    = (const float*)d_in[11];
    const float* Wlin  = (const float*)d_in[12];
    const float* blin  = (const float*)d_in[13];
    float* out = (float*)d_out;

    // ---- workspace layout (identical to R7) --------------------------------
    char* p = (char*)d_ws;
    int*   cursor = (int*)p;               p += 1024 * 4;
    float* pooled = (float*)p;             p += (size_t)NUM_GRAPHS * 32 * 4;
    int*   rowptr = (int*)p;               p += (size_t)NB2 * RPW * 4;
    p = align16p(p);
    int*   csr    = (int*)p;               p += (size_t)NB2 * CAPB * 4;
    int*   pairbuf= (int*)p;
    __half* t1    = (__half*)pairbuf;                                  // alias
    float*  r1    = (float*)((char*)pairbuf + (size_t)N_NODES * 16 * 2);
    p += (size_t)NB2 * CAPB * 4;
    __half* t2    = (__half*)p;            p += (size_t)N_NODES * 32 * 2;
    float*  r2    = (float*)align16p(p);   p = (char*)r2 + (size_t)N_NODES * 32 * 4;
    float*  agg   = (float*)p;
    __half* t3    = t2;   // in-place
    float*  r3    = r2;   // in-place

    hipMemsetAsync(pooled, 0, (size_t)NUM_GRAPHS * 32 * 4, stream);

    // Bucketed CSR build: no count pass, no global scan
    k_init_cursor  <<<1, 1024, 0, stream>>>(cursor);
    k_scatter_pairs<<<NBLK_BIN, 256, 0, stream>>>(ei, cursor, pairbuf);
    k_build_csr    <<<NB2, 256, 0, stream>>>(cursor, pairbuf, rowptr, csr);

    // Layer pipeline
    k_transform1_mfma<<<(6250 + 3) / 4, 256, 0, stream>>>(x, W1n, W1r, b1, t1, r1);
    k_gather16b<<<N_NODES * 8 / 256, 256, 0, stream>>>(rowptr, csr,
                    (const __half2*)t1, agg);
    k_combine1_transform2<<<N_NODES / 4, 256, 0, stream>>>(r1, agg, W2n, W2r, b2,
                                                           t2, r2);
    k_gather32h<<<N_NODES * 16 / 256, 256, 0, stream>>>(rowptr, csr,
                    (const __half2*)t2, agg, 0, 0);
    k_gather32h<<<N_NODES * 16 / 256, 256, 0, stream>>>(rowptr, csr,
                    (const __half2*)t2, agg, NBH, 1);
    k_combine2_transform3<<<N_NODES / 4, 256, 0, stream>>>(r2, agg, W3n, W3r, b3,
                                                           t3, r3);
    k_gather32h<<<N_NODES * 16 / 256, 256, 0, stream>>>(rowptr, csr,
                    (const __half2*)t3, agg, 0, 0);
    k_gather32h<<<N_NODES * 16 / 256, 256, 0, stream>>>(rowptr, csr,
                    (const __half2*)t3, agg, NBH, 1);
    k_combine3_pool<<<N_NODES * 32 / 256, 256, 0, stream>>>(r3, agg, batch, pooled);
    k_final     <<<NUM_GRAPHS, 64, 0, stream>>>(pooled, Wlin, blin, out);
}

// Round 11
// 467.046 us; speedup vs baseline: 1.0456x; 1.0456x over previous
//
#include <hip/hip_runtime.h>
#include <hip/hip_fp16.h>

#define N_NODES   100000
#define N_EDGES   3200000
#define IN_CH     128
#define NUM_GRAPHS 1000
#define NHALF     50000    // src-half boundary
#define NBH       391      // dst-buckets per src-half (256 nodes each)
#define NB2       782      // total buckets = 2 src-halves x 391
#define CAPB      4608     // per-bucket window capacity (mean 4096, +8 sigma)
#define CHUNK     4096     // edges per block in the binning pass
#define NBLK_BIN  782      // ceil(3200000/4096)
#define RPW       257      // rowptr words per bucket (256 nodes + sentinel)

typedef __attribute__((ext_vector_type(8))) _Float16 half8;
typedef __attribute__((ext_vector_type(4))) float    float4v;

// ---------------------------------------------------------------------------
// Scatter: LDS counting sort per 4096-edge chunk, linear write-out into
// per-bucket windows. 1024 threads/block (R10 post-mortem: 256-thread version
// was serial-loop + occupancy bound at 12 waves/CU; this gives 4 iters/loop
// and 2 blocks/CU x 16 waves = 32 waves/CU). cursor[] is pre-zeroed by the
// memset; window base b*CAPB is added here (k_init_cursor launch deleted).
// ---------------------------------------------------------------------------
__global__ __launch_bounds__(1024, 2) void k_scatter_pairs(
    const int* __restrict__ ei, int* __restrict__ cursor,
    int* __restrict__ pairbuf)
{
    __shared__ int h[NB2];          // counts, then local cursor
    __shared__ int gbase[NB2];
    __shared__ int sstart[NB2 + 1]; // local exclusive scan
    __shared__ int sa[1024];
    __shared__ int sb[1024];
    __shared__ int ebuf[CHUNK];
    __shared__ unsigned short sbk[CHUNK];
    int tid = threadIdx.x;
    if (tid < NB2) h[tid] = 0;
    __syncthreads();
    int base = blockIdx.x * CHUNK;
    int end = min(base + CHUNK, N_EDGES);
    int cntE = end - base;
    // histogram: 4 edges/thread
#pragma unroll
    for (int r = 0; r < 4; ++r) {
        int e = base + tid + 1024 * r;
        if (e < end) {
            int src = ei[e];
            int dst = ei[N_EDGES + e];
            int b = ((src >= NHALF) ? NBH : 0) + (dst >> 8);
            atomicAdd(&h[b], 1);
        }
    }
    __syncthreads();
    // inclusive Hillis-Steele scan, 1 element/thread over 1024 (NB2 padded)
    sa[tid] = (tid < NB2) ? h[tid] : 0;
    __syncthreads();
    int* A = sa; int* B = sb;
    for (int off = 1; off < 1024; off <<= 1) {
        int v = A[tid] + ((tid >= off) ? A[tid - off] : 0);
        __syncthreads();
        B[tid] = v;
        __syncthreads();
        int* tmp = A; A = B; B = tmp;
    }
    if (tid == 0) sstart[0] = 0;
    if (tid < NB2) sstart[tid + 1] = A[tid];
    __syncthreads();
    // reserve global windows; reset h as local cursor
    if (tid < NB2) {
        int c = sstart[tid + 1] - sstart[tid];
        gbase[tid] = c ? (tid * CAPB + atomicAdd(&cursor[tid], c)) : 0;
        h[tid] = 0;
    }
    __syncthreads();
    // place edges bucket-sorted into ebuf; record bucket id per slot
#pragma unroll
    for (int r = 0; r < 4; ++r) {
        int e = base + tid + 1024 * r;
        if (e < end) {
            int src = ei[e];
            int dst = ei[N_EDGES + e];
            int b = ((src >= NHALF) ? NBH : 0) + (dst >> 8);
            int off = atomicAdd(&h[b], 1);
            int slot = sstart[b] + off;
            ebuf[slot] = src | ((dst & 255) << 17);
            sbk[slot] = (unsigned short)b;
        }
    }
    __syncthreads();
    // linear write-out, direct bucket lookup
#pragma unroll
    for (int r = 0; r < 4; ++r) {
        int i = tid + 1024 * r;
        if (i < cntE) {
            int b = sbk[i];
            pairbuf[gbase[b] + (i - sstart[b])] = ebuf[i];
        }
    }
}

// ---------------------------------------------------------------------------
// Build CSR: one block per bucket window. cursor[b] now holds the COUNT
// (scatter adds the base itself). LDS histogram over 256 local dst, scan ->
// rowptr[b*257+i] (+ sentinel), scatter src ids into the contiguous window.
// ---------------------------------------------------------------------------
__global__ __launch_bounds__(256) void k_build_csr(const int* __restrict__ cursor,
                                                   const int* __restrict__ pairbuf,
                                                   int* __restrict__ rowptr,
                                                   int* __restrict__ csr)
{
    __shared__ int cnt[256];
    __shared__ int scanv[256];
    __shared__ int ebuf[CAPB];
    int b = blockIdx.x;
    int base = b * CAPB;
    int cntE = cursor[b];
    int tid = threadIdx.x;
    cnt[tid] = 0;
    __syncthreads();
    for (int i = tid; i < cntE; i += 256) {
        int p = pairbuf[base + i];
        ebuf[i] = p;
        atomicAdd(&cnt[(p >> 17) & 255], 1);
    }
    __syncthreads();
    int v = cnt[tid];
    scanv[tid] = v;
    __syncthreads();
    for (int off = 1; off < 256; off <<= 1) {
        int t = (tid >= off) ? scanv[tid - off] : 0;
        __syncthreads();
        scanv[tid] += t;
        __syncthreads();
    }
    int ex = scanv[tid] - v;           // exclusive within bucket
    rowptr[b * RPW + tid] = base + ex;
    if (tid == 0) rowptr[b * RPW + 256] = base + cntE;
    __syncthreads();
    cnt[tid] = ex;                     // local cursor
    __syncthreads();
    for (int i = tid; i < cntE; i += 256) {
        int p = ebuf[i];
        int pos = atomicAdd(&cnt[(p >> 17) & 255], 1);
        csr[base + pos] = p & 0x1FFFF;
    }
}

// ---------------------------------------------------------------------------
// transform1 via MFMA f16: t1 = half(x @ W1_nbr); r1 = x @ W1_root + b1.
// ---------------------------------------------------------------------------
__global__ __launch_bounds__(256) void k_transform1_mfma(
    const float* __restrict__ x,
    const float* __restrict__ W1n, const float* __restrict__ W1r,
    const float* __restrict__ b1,
    __half* __restrict__ t1, float* __restrict__ r1)
{
    int wave = threadIdx.x >> 6;
    int lane = threadIdx.x & 63;
    int tile = blockIdx.x * 4 + wave;
    int node0 = tile * 16;
    int m = lane & 15, quad = lane >> 4;
    int row = node0 + m;
    if (row >= N_NODES) row = N_NODES - 1;     // clamp (stores are guarded)
    const float* xr = x + (size_t)row * IN_CH + quad * 8;

    float4v acc_n = {0.f, 0.f, 0.f, 0.f};
    float4v acc_r = {0.f, 0.f, 0.f, 0.f};
#pragma unroll
    for (int kc = 0; kc < 4; ++kc) {
        half8 a, bn, br;
        const float* xp = xr + kc * 32;
#pragma unroll
        for (int j = 0; j < 8; ++j) a[j] = (_Float16)xp[j];
        int kbase = kc * 32 + quad * 8;
#pragma unroll
        for (int j = 0; j < 8; ++j) {
            bn[j] = (_Float16)W1n[(kbase + j) * 16 + m];
            br[j] = (_Float16)W1r[(kbase + j) * 16 + m];
        }
        acc_n = __builtin_amdgcn_mfma_f32_16x16x32_f16(a, bn, acc_n, 0, 0, 0);
        acc_r = __builtin_amdgcn_mfma_f32_16x16x32_f16(a, br, acc_r, 0, 0, 0);
    }
    float bias = b1[m];
#pragma unroll
    for (int reg = 0; reg < 4; ++reg) {
        int node = node0 + quad * 4 + reg;
        if (node < N_NODES) {
            t1[node * 16 + m] = __float2half_rn(acc_n[reg]);
            r1[node * 16 + m] = acc_r[reg] + bias;
        }
    }
}

// ---------------------------------------------------------------------------
// Layer-1 gather: 16 channels, both src-halves in one pass (t1 = 3.2 MB,
// L2-resident). 8 lanes/node (half2), 8-deep unroll. Register accumulate.
// ---------------------------------------------------------------------------
__global__ __launch_bounds__(256) void k_gather16b(
    const int* __restrict__ rowptr, const int* __restrict__ csr,
    const __half2* __restrict__ t, float* __restrict__ agg)
{
    int tid = blockIdx.x * 256 + threadIdx.x;      // exactly N_NODES*8
    int n = tid >> 3, cp = tid & 7;
    float2 a0 = {0.f,0.f}, a1 = {0.f,0.f}, a2 = {0.f,0.f}, a3 = {0.f,0.f};
#pragma unroll
    for (int hh = 0; hh < 2; ++hh) {
        int idx = (hh * NBH + (n >> 8)) * RPW + (n & 255);
        int j = rowptr[idx], end = rowptr[idx + 1];
        for (; j + 7 < end; j += 8) {
            int s0 = __builtin_nontemporal_load(&csr[j]);
            int s1 = __builtin_nontemporal_load(&csr[j + 1]);
            int s2 = __builtin_nontemporal_load(&csr[j + 2]);
            int s3 = __builtin_nontemporal_load(&csr[j + 3]);
            int s4 = __builtin_nontemporal_load(&csr[j + 4]);
            int s5 = __builtin_nontemporal_load(&csr[j + 5]);
            int s6 = __builtin_nontemporal_load(&csr[j + 6]);
            int s7 = __builtin_nontemporal_load(&csr[j + 7]);
            float2 f0 = __half22float2(t[s0 * 8 + cp]);
            float2 f1 = __half22float2(t[s1 * 8 + cp]);
            float2 f2 = __half22float2(t[s2 * 8 + cp]);
            float2 f3 = __half22float2(t[s3 * 8 + cp]);
            float2 f4 = __half22float2(t[s4 * 8 + cp]);
            float2 f5 = __half22float2(t[s5 * 8 + cp]);
            float2 f6 = __half22float2(t[s6 * 8 + cp]);
            float2 f7 = __half22float2(t[s7 * 8 + cp]);
            a0.x += f0.x; a0.y += f0.y;  a1.x += f1.x; a1.y += f1.y;
            a2.x += f2.x; a2.y += f2.y;  a3.x += f3.x; a3.y += f3.y;
            a0.x += f4.x; a0.y += f4.y;  a1.x += f5.x; a1.y += f5.y;
            a2.x += f6.x; a2.y += f6.y;  a3.x += f7.x; a3.y += f7.y;
        }
        for (; j < end; ++j) {
            float2 f = __half22float2(t[__builtin_nontemporal_load(&csr[j]) * 8 + cp]);
            a0.x += f.x; a0.y += f.y;
        }
    }
    float rx = (a0.x + a1.x) + (a2.x + a3.x);
    float ry = (a0.y + a1.y) + (a2.y + a3.y);
    __builtin_nontemporal_store(rx, &agg[n * 16 + 2 * cp]);
    __builtin_nontemporal_store(ry, &agg[n * 16 + 2 * cp + 1]);
}

// ---------------------------------------------------------------------------
// Layer-2/3 gather: 32 channels, ONE src-half per launch (random reads
// confined to a 3.2 MB table half -> per-XCD L2 resident). 16 lanes/node.
// bbase = 0 (half A, overwrite agg) or NBH (half B, accumulate).
// ---------------------------------------------------------------------------
__global__ __launch_bounds__(256) void k_gather32h(
    const int* __restrict__ rowptr, const int* __restrict__ csr,
    const __half2* __restrict__ t, float* __restrict__ agg,
    int bbase, int accflag)
{
    int tid = blockIdx.x * 256 + threadIdx.x;      // exactly N_NODES*16
    int n = tid >> 4, cp = tid & 15;
    int idx = (bbase + (n >> 8)) * RPW + (n & 255);
    int j = rowptr[idx], end = rowptr[idx + 1];
    float2 a0 = {0.f,0.f}, a1 = {0.f,0.f}, a2 = {0.f,0.f}, a3 = {0.f,0.f};
    for (; j + 7 < end; j += 8) {
        int s0 = __builtin_nontemporal_load(&csr[j]);
        int s1 = __builtin_nontemporal_load(&csr[j + 1]);
        int s2 = __builtin_nontemporal_load(&csr[j + 2]);
        int s3 = __builtin_nontemporal_load(&csr[j + 3]);
        int s4 = __builtin_nontemporal_load(&csr[j + 4]);
        int s5 = __builtin_nontemporal_load(&csr[j + 5]);
        int s6 = __builtin_nontemporal_load(&csr[j + 6]);
        int s7 = __builtin_nontemporal_load(&csr[j + 7]);
        float2 f0 = __half22float2(t[s0 * 16 + cp]);
        float2 f1 = __half22float2(t[s1 * 16 + cp]);
        float2 f2 = __half22float2(t[s2 * 16 + cp]);
        float2 f3 = __half22float2(t[s3 * 16 + cp]);
        float2 f4 = __half22float2(t[s4 * 16 + cp]);
        float2 f5 = __half22float2(t[s5 * 16 + cp]);
        float2 f6 = __half22float2(t[s6 * 16 + cp]);
        float2 f7 = __half22float2(t[s7 * 16 + cp]);
        a0.x += f0.x; a0.y += f0.y;  a1.x += f1.x; a1.y += f1.y;
        a2.x += f2.x; a2.y += f2.y;  a3.x += f3.x; a3.y += f3.y;
        a0.x += f4.x; a0.y += f4.y;  a1.x += f5.x; a1.y += f5.y;
        a2.x += f6.x; a2.y += f6.y;  a3.x += f7.x; a3.y += f7.y;
    }
    for (; j < end; ++j) {
        float2 f = __half22float2(t[__builtin_nontemporal_load(&csr[j]) * 16 + cp]);
        a0.x += f.x; a0.y += f.y;
    }
    float rx = (a0.x + a1.x) + (a2.x + a3.x);
    float ry = (a0.y + a1.y) + (a2.y + a3.y);
    if (accflag) {
        rx += __builtin_nontemporal_load(&agg[n * 32 + 2 * cp]);
        ry += __builtin_nontemporal_load(&agg[n * 32 + 2 * cp + 1]);
    }
    __builtin_nontemporal_store(rx, &agg[n * 32 + 2 * cp]);
    __builtin_nontemporal_store(ry, &agg[n * 32 + 2 * cp + 1]);
}

// ---------------------------------------------------------------------------
// K3: h1 = relu(r1 + agg16); t2 = half(h1 @ W2_nbr); r2 = h1 @ W2_root + b2
// ---------------------------------------------------------------------------
__global__ __launch_bounds__(256) void k_combine1_transform2(
    const float* __restrict__ r1, const float* __restrict__ agg1,
    const float* __restrict__ W2n, const float* __restrict__ W2r,
    const float* __restrict__ b2,
    __half* __restrict__ t2, float* __restrict__ r2)
{
    __shared__ float sW[16 * 64];   // [k][c]
    __shared__ float sh[4 * 16];

    for (int i = threadIdx.x; i < 16 * 64; i += 256) {
        int k = i >> 6, c = i & 63;
        sW[i] = (c < 32) ? W2n[k * 32 + c] : W2r[k * 32 + (c - 32)];
    }
    int node0 = blockIdx.x * 4;
    if (threadIdx.x < 64) {
        int idx = node0 * 16 + threadIdx.x;
        float v = r1[idx] + agg1[idx];
        sh[threadIdx.x] = v > 0.f ? v : 0.f;
    }
    __syncthreads();

    int c  = threadIdx.x & 63;
    int nl = threadIdx.x >> 6;
    const float* hr = &sh[nl * 16];
    float acc = 0.f;
#pragma unroll
    for (int k = 0; k < 16; ++k) acc += hr[k] * sW[k * 64 + c];

    int node = node0 + nl;
    if (c < 32) t2[node * 32 + c] = __float2half_rn(acc);
    else        r2[node * 32 + (c - 32)] = acc + b2[c - 32];
}

// ---------------------------------------------------------------------------
// K5: h2 = relu(r2 + agg32); t3 = half(h2 @ W3_nbr); r3 = h2 @ W3_root + b3
// t3/r3 alias t2/r2 — block reads its slice to LDS, barrier, overwrites.
// ---------------------------------------------------------------------------
__global__ __launch_bounds__(256) void k_combine2_transform3(
    const float* __restrict__ r2, const float* __restrict__ agg2,
    const float* __restrict__ W3n, const float* __restrict__ W3r,
    const float* __restrict__ b3,
    __half* __restrict__ t3, float* __restrict__ r3)
{
    __shared__ float sW[32 * 64];
    __shared__ float sh[4 * 32];

    for (int i = threadIdx.x; i < 32 * 64; i += 256) {
        int k = i >> 6, c = i & 63;
        sW[i] = (c < 32) ? W3n[k * 32 + c] : W3r[k * 32 + (c - 32)];
    }
    int node0 = blockIdx.x * 4;
    if (threadIdx.x < 128) {
        int idx = node0 * 32 + threadIdx.x;
        float v = r2[idx] + agg2[idx];
        sh[threadIdx.x] = v > 0.f ? v : 0.f;
    }
    __syncthreads();

    int c  = threadIdx.x & 63;
    int nl = threadIdx.x >> 6;
    const float* hr = &sh[nl * 32];
    float acc = 0.f;
#pragma unroll
    for (int k = 0; k < 32; ++k) acc += hr[k] * sW[k * 64 + c];

    int node = node0 + nl;
    if (c < 32) t3[node * 32 + c] = __float2half_rn(acc);
    else        r3[node * 32 + (c - 32)] = acc + b3[c - 32];
}

// ---------------------------------------------------------------------------
// K7: h3 = relu(r3 + agg32); pooled[batch[n]] += h3[n]
// ---------------------------------------------------------------------------
__global__ __launch_bounds__(256) void k_combine3_pool(
    const float* __restrict__ r3, const float* __restrict__ agg3,
    const int* __restrict__ batch, float* __restrict__ pooled)
{
    int tid = blockIdx.x * 256 + threadIdx.x;
    if (tid >= N_NODES * 32) return;
    int n = tid >> 5, c = tid & 31;
    float v = r3[tid] + agg3[tid];
    v = v > 0.f ? v : 0.f;
    atomicAdd(&pooled[batch[n] * 32 + c], v);
}

// ---------------------------------------------------------------------------
// K8: out = pooled @ Wlin + blin   (1000x32 @ 32x64)
// ---------------------------------------------------------------------------
__global__ __launch_bounds__(64) void k_final(
    const float* __restrict__ pooled, const float* __restrict__ Wlin,
    const float* __restrict__ blin, float* __restrict__ out)
{
    int g = blockIdx.x;
    int o = threadIdx.x;
    float acc = blin[o];
#pragma unroll
    for (int k = 0; k < 32; ++k) acc += pooled[g * 32 + k] * Wlin[k * 64 + o];
    out[g * 64 + o] = acc;
}

static inline char* align16p(char* p) {
    return (char*)(((uintptr_t)p + 15) & ~(uintptr_t)15);
}

extern "C" void kernel_launch(void* const* d_in, const int* in_sizes, int n_in,
                              void* d_out, int out_size, void* d_ws, size_t ws_size,
                              hipStream_t stream) {
    const float* x     = (const float*)d_in[0];
    const int*   ei    = (const int*)d_in[1];
    const int*   batch = (const int*)d_in[2];
    const float* W1r   = (const float*)d_in[3];
    const float* W1n   = (const float*)d_in[4];
    const float* b1    = (const float*)d_in[5];
    const float* W2r   = (const float*)d_in[6];
    const float* W2n   = (const float*)d_in[7];
    const float* b2    = (const float*)d_in[8];
    const float* W3r   = (const float*)d_in[9];
    const float* W3n   = (const float*)d_in[10];
    const float* b3    = (const float*)d_in[11];
    const float* Wlin  = (const float*)d_in[12];
    const float* blin  = (const float*)d_in[13];
    float* out = (float*)d_out;

    // ---- workspace layout (identical to R10) -------------------------------
    char* p = (char*)d_ws;
    int*   cursor = (int*)p;               p += 1024 * 4;
    float* pooled = (float*)p;             p += (size_t)NUM_GRAPHS * 32 * 4;
    int*   rowptr = (int*)p;               p += (size_t)NB2 * RPW * 4;
    p = align16p(p);
    int*   csr    = (int*)p;               p += (size_t)NB2 * CAPB * 4;
    int*   pairbuf= (int*)p;
    __half* t1    = (__half*)pairbuf;                                  // alias
    float*  r1    = (float*)((char*)pairbuf + (size_t)N_NODES * 16 * 2);
    p += (size_t)NB2 * CAPB * 4;
    __half* t2    = (__half*)p;            p += (size_t)N_NODES * 32 * 2;
    float*  r2    = (float*)align16p(p);   p = (char*)r2 + (size_t)N_NODES * 32 * 4;
    float*  agg   = (float*)p;
    __half* t3    = t2;   // in-place
    float*  r3    = r2;   // in-place

    // one memset zeroes cursor (adjacent) + pooled; k_init_cursor deleted
    hipMemsetAsync(cursor, 0, (1024 + (size_t)NUM_GRAPHS * 32) * 4, stream);

    // Bucketed CSR build
    k_scatter_pairs<<<NBLK_BIN, 1024, 0, stream>>>(ei, cursor, pairbuf);
    k_build_csr    <<<NB2, 256, 0, stream>>>(cursor, pairbuf, rowptr, csr);

    // Layer pipeline
    k_transform1_mfma<<<(6250 + 3) / 4, 256, 0, stream>>>(x, W1n, W1r, b1, t1, r1);
    k_gather16b<<<N_NODES * 8 / 256, 256, 0, stream>>>(rowptr, csr,
                    (const __half2*)t1, agg);
    k_combine1_transform2<<<N_NODES / 4, 256, 0, stream>>>(r1, agg, W2n, W2r, b2,
                                                           t2, r2);
    k_gather32h<<<N_NODES * 16 / 256, 256, 0, stream>>>(rowptr, csr,
                    (const __half2*)t2, agg, 0, 0);
    k_gather32h<<<N_NODES * 16 / 256, 256, 0, stream>>>(rowptr, csr,
                    (const __half2*)t2, agg, NBH, 1);
    k_combine2_transform3<<<N_NODES / 4, 256, 0, stream>>>(r2, agg, W3n, W3r, b3,
                                                           t3, r3);
    k_gather32h<<<N_NODES * 16 / 256, 256, 0, stream>>>(rowptr, csr,
                    (const __half2*)t3, agg, 0, 0);
    k_gather32h<<<N_NODES * 16 / 256, 256, 0, stream>>>(rowptr, csr,
                    (const __half2*)t3, agg, NBH, 1);
    k_combine3_pool<<<N_NODES * 32 / 256, 256, 0, stream>>>(r3, agg, batch, pooled);
    k_final     <<<NUM_GRAPHS, 64, 0, stream>>>(pooled, Wlin, blin, out);
}

// Round 12
// 422.027 us; speedup vs baseline: 1.1572x; 1.1067x over previous
//
#include <hip/hip_runtime.h>
#include <hip/hip_fp16.h>

#define N_NODES   100000
#define N_EDGES   3200000
#define IN_CH     128
#define NUM_GRAPHS 1000
#define NHALF     50000    // src-half boundary
#define NBH       391      // dst-buckets per src-half (256 nodes each)
#define NB2       782      // total buckets = 2 src-halves x 391
#define CAPB      4608     // per-bucket window capacity (mean 4096, +8 sigma)
#define CHUNK     4096     // edges per block in the binning pass
#define NBLK_BIN  782      // ceil(3200000/4096)
#define RPW       257      // rowptr words per bucket (256 nodes + sentinel)

typedef __attribute__((ext_vector_type(8))) _Float16 half8;
typedef __attribute__((ext_vector_type(4))) float    float4v;

// ---------------------------------------------------------------------------
// Scatter: LDS counting sort per 4096-edge chunk, linear write-out into
// per-bucket windows. 1024 threads/block, 2 blocks/CU (R11-proven).
// ---------------------------------------------------------------------------
__global__ __launch_bounds__(1024, 2) void k_scatter_pairs(
    const int* __restrict__ ei, int* __restrict__ cursor,
    int* __restrict__ pairbuf)
{
    __shared__ int h[NB2];          // counts, then local cursor
    __shared__ int gbase[NB2];
    __shared__ int sstart[NB2 + 1]; // local exclusive scan
    __shared__ int sa[1024];
    __shared__ int sb[1024];
    __shared__ int ebuf[CHUNK];
    __shared__ unsigned short sbk[CHUNK];
    int tid = threadIdx.x;
    if (tid < NB2) h[tid] = 0;
    __syncthreads();
    int base = blockIdx.x * CHUNK;
    int end = min(base + CHUNK, N_EDGES);
    int cntE = end - base;
#pragma unroll
    for (int r = 0; r < 4; ++r) {
        int e = base + tid + 1024 * r;
        if (e < end) {
            int src = ei[e];
            int dst = ei[N_EDGES + e];
            int b = ((src >= NHALF) ? NBH : 0) + (dst >> 8);
            atomicAdd(&h[b], 1);
        }
    }
    __syncthreads();
    sa[tid] = (tid < NB2) ? h[tid] : 0;
    __syncthreads();
    int* A = sa; int* B = sb;
    for (int off = 1; off < 1024; off <<= 1) {
        int v = A[tid] + ((tid >= off) ? A[tid - off] : 0);
        __syncthreads();
        B[tid] = v;
        __syncthreads();
        int* tmp = A; A = B; B = tmp;
    }
    if (tid == 0) sstart[0] = 0;
    if (tid < NB2) sstart[tid + 1] = A[tid];
    __syncthreads();
    if (tid < NB2) {
        int c = sstart[tid + 1] - sstart[tid];
        gbase[tid] = c ? (tid * CAPB + atomicAdd(&cursor[tid], c)) : 0;
        h[tid] = 0;
    }
    __syncthreads();
#pragma unroll
    for (int r = 0; r < 4; ++r) {
        int e = base + tid + 1024 * r;
        if (e < end) {
            int src = ei[e];
            int dst = ei[N_EDGES + e];
            int b = ((src >= NHALF) ? NBH : 0) + (dst >> 8);
            int off = atomicAdd(&h[b], 1);
            int slot = sstart[b] + off;
            ebuf[slot] = src | ((dst & 255) << 17);
            sbk[slot] = (unsigned short)b;
        }
    }
    __syncthreads();
#pragma unroll
    for (int r = 0; r < 4; ++r) {
        int i = tid + 1024 * r;
        if (i < cntE) {
            int b = sbk[i];
            pairbuf[gbase[b] + (i - sstart[b])] = ebuf[i];
        }
    }
}

// ---------------------------------------------------------------------------
// Build CSR: one block per bucket window. cursor[b] holds the COUNT.
// ---------------------------------------------------------------------------
__global__ __launch_bounds__(256) void k_build_csr(const int* __restrict__ cursor,
                                                   const int* __restrict__ pairbuf,
                                                   int* __restrict__ rowptr,
                                                   int* __restrict__ csr)
{
    __shared__ int cnt[256];
    __shared__ int scanv[256];
    __shared__ int ebuf[CAPB];
    int b = blockIdx.x;
    int base = b * CAPB;
    int cntE = cursor[b];
    int tid = threadIdx.x;
    cnt[tid] = 0;
    __syncthreads();
    for (int i = tid; i < cntE; i += 256) {
        int p = pairbuf[base + i];
        ebuf[i] = p;
        atomicAdd(&cnt[(p >> 17) & 255], 1);
    }
    __syncthreads();
    int v = cnt[tid];
    scanv[tid] = v;
    __syncthreads();
    for (int off = 1; off < 256; off <<= 1) {
        int t = (tid >= off) ? scanv[tid - off] : 0;
        __syncthreads();
        scanv[tid] += t;
        __syncthreads();
    }
    int ex = scanv[tid] - v;
    rowptr[b * RPW + tid] = base + ex;
    if (tid == 0) rowptr[b * RPW + 256] = base + cntE;
    __syncthreads();
    cnt[tid] = ex;
    __syncthreads();
    for (int i = tid; i < cntE; i += 256) {
        int p = ebuf[i];
        int pos = atomicAdd(&cnt[(p >> 17) & 255], 1);
        csr[base + pos] = p & 0x1FFFF;
    }
}

// ---------------------------------------------------------------------------
// transform1 via MFMA f16: t1 = half(x @ W1_nbr); r1 = x @ W1_root + b1.
// ---------------------------------------------------------------------------
__global__ __launch_bounds__(256) void k_transform1_mfma(
    const float* __restrict__ x,
    const float* __restrict__ W1n, const float* __restrict__ W1r,
    const float* __restrict__ b1,
    __half* __restrict__ t1, float* __restrict__ r1)
{
    int wave = threadIdx.x >> 6;
    int lane = threadIdx.x & 63;
    int tile = blockIdx.x * 4 + wave;
    int node0 = tile * 16;
    int m = lane & 15, quad = lane >> 4;
    int row = node0 + m;
    if (row >= N_NODES) row = N_NODES - 1;     // clamp (stores are guarded)
    const float* xr = x + (size_t)row * IN_CH + quad * 8;

    float4v acc_n = {0.f, 0.f, 0.f, 0.f};
    float4v acc_r = {0.f, 0.f, 0.f, 0.f};
#pragma unroll
    for (int kc = 0; kc < 4; ++kc) {
        half8 a, bn, br;
        const float* xp = xr + kc * 32;
#pragma unroll
        for (int j = 0; j < 8; ++j) a[j] = (_Float16)xp[j];
        int kbase = kc * 32 + quad * 8;
#pragma unroll
        for (int j = 0; j < 8; ++j) {
            bn[j] = (_Float16)W1n[(kbase + j) * 16 + m];
            br[j] = (_Float16)W1r[(kbase + j) * 16 + m];
        }
        acc_n = __builtin_amdgcn_mfma_f32_16x16x32_f16(a, bn, acc_n, 0, 0, 0);
        acc_r = __builtin_amdgcn_mfma_f32_16x16x32_f16(a, br, acc_r, 0, 0, 0);
    }
    float bias = b1[m];
#pragma unroll
    for (int reg = 0; reg < 4; ++reg) {
        int node = node0 + quad * 4 + reg;
        if (node < N_NODES) {
            t1[node * 16 + m] = __float2half_rn(acc_n[reg]);
            r1[node * 16 + m] = acc_r[reg] + bias;
        }
    }
}

// ---------------------------------------------------------------------------
// Layer-1 gather: 16 channels, both src-halves in one pass (t1 = 3.2 MB,
// L2-resident). 8 lanes/node (half2), 8-deep unroll. Register accumulate.
// ---------------------------------------------------------------------------
__global__ __launch_bounds__(256) void k_gather16b(
    const int* __restrict__ rowptr, const int* __restrict__ csr,
    const __half2* __restrict__ t, float* __restrict__ agg)
{
    int tid = blockIdx.x * 256 + threadIdx.x;      // exactly N_NODES*8
    int n = tid >> 3, cp = tid & 7;
    float2 a0 = {0.f,0.f}, a1 = {0.f,0.f}, a2 = {0.f,0.f}, a3 = {0.f,0.f};
#pragma unroll
    for (int hh = 0; hh < 2; ++hh) {
        int idx = (hh * NBH + (n >> 8)) * RPW + (n & 255);
        int j = rowptr[idx], end = rowptr[idx + 1];
        for (; j + 7 < end; j += 8) {
            int s0 = __builtin_nontemporal_load(&csr[j]);
            int s1 = __builtin_nontemporal_load(&csr[j + 1]);
            int s2 = __builtin_nontemporal_load(&csr[j + 2]);
            int s3 = __builtin_nontemporal_load(&csr[j + 3]);
            int s4 = __builtin_nontemporal_load(&csr[j + 4]);
            int s5 = __builtin_nontemporal_load(&csr[j + 5]);
            int s6 = __builtin_nontemporal_load(&csr[j + 6]);
            int s7 = __builtin_nontemporal_load(&csr[j + 7]);
            float2 f0 = __half22float2(t[s0 * 8 + cp]);
            float2 f1 = __half22float2(t[s1 * 8 + cp]);
            float2 f2 = __half22float2(t[s2 * 8 + cp]);
            float2 f3 = __half22float2(t[s3 * 8 + cp]);
            float2 f4 = __half22float2(t[s4 * 8 + cp]);
            float2 f5 = __half22float2(t[s5 * 8 + cp]);
            float2 f6 = __half22float2(t[s6 * 8 + cp]);
            float2 f7 = __half22float2(t[s7 * 8 + cp]);
            a0.x += f0.x; a0.y += f0.y;  a1.x += f1.x; a1.y += f1.y;
            a2.x += f2.x; a2.y += f2.y;  a3.x += f3.x; a3.y += f3.y;
            a0.x += f4.x; a0.y += f4.y;  a1.x += f5.x; a1.y += f5.y;
            a2.x += f6.x; a2.y += f6.y;  a3.x += f7.x; a3.y += f7.y;
        }
        for (; j < end; ++j) {
            float2 f = __half22float2(t[__builtin_nontemporal_load(&csr[j]) * 8 + cp]);
            a0.x += f.x; a0.y += f.y;
        }
    }
    float rx = (a0.x + a1.x) + (a2.x + a3.x);
    float ry = (a0.y + a1.y) + (a2.y + a3.y);
    __builtin_nontemporal_store(rx, &agg[n * 16 + 2 * cp]);
    __builtin_nontemporal_store(ry, &agg[n * 16 + 2 * cp + 1]);
}

// ---------------------------------------------------------------------------
// Layer-2/3 gather: 32 channels, ONE src-half per launch. 16 lanes/node.
// ---------------------------------------------------------------------------
__global__ __launch_bounds__(256) void k_gather32h(
    const int* __restrict__ rowptr, const int* __restrict__ csr,
    const __half2* __restrict__ t, float* __restrict__ agg,
    int bbase, int accflag)
{
    int tid = blockIdx.x * 256 + threadIdx.x;      // exactly N_NODES*16
    int n = tid >> 4, cp = tid & 15;
    int idx = (bbase + (n >> 8)) * RPW + (n & 255);
    int j = rowptr[idx], end = rowptr[idx + 1];
    float2 a0 = {0.f,0.f}, a1 = {0.f,0.f}, a2 = {0.f,0.f}, a3 = {0.f,0.f};
    for (; j + 7 < end; j += 8) {
        int s0 = __builtin_nontemporal_load(&csr[j]);
        int s1 = __builtin_nontemporal_load(&csr[j + 1]);
        int s2 = __builtin_nontemporal_load(&csr[j + 2]);
        int s3 = __builtin_nontemporal_load(&csr[j + 3]);
        int s4 = __builtin_nontemporal_load(&csr[j + 4]);
        int s5 = __builtin_nontemporal_load(&csr[j + 5]);
        int s6 = __builtin_nontemporal_load(&csr[j + 6]);
        int s7 = __builtin_nontemporal_load(&csr[j + 7]);
        float2 f0 = __half22float2(t[s0 * 16 + cp]);
        float2 f1 = __half22float2(t[s1 * 16 + cp]);
        float2 f2 = __half22float2(t[s2 * 16 + cp]);
        float2 f3 = __half22float2(t[s3 * 16 + cp]);
        float2 f4 = __half22float2(t[s4 * 16 + cp]);
        float2 f5 = __half22float2(t[s5 * 16 + cp]);
        float2 f6 = __half22float2(t[s6 * 16 + cp]);
        float2 f7 = __half22float2(t[s7 * 16 + cp]);
        a0.x += f0.x; a0.y += f0.y;  a1.x += f1.x; a1.y += f1.y;
        a2.x += f2.x; a2.y += f2.y;  a3.x += f3.x; a3.y += f3.y;
        a0.x += f4.x; a0.y += f4.y;  a1.x += f5.x; a1.y += f5.y;
        a2.x += f6.x; a2.y += f6.y;  a3.x += f7.x; a3.y += f7.y;
    }
    for (; j < end; ++j) {
        float2 f = __half22float2(t[__builtin_nontemporal_load(&csr[j]) * 16 + cp]);
        a0.x += f.x; a0.y += f.y;
    }
    float rx = (a0.x + a1.x) + (a2.x + a3.x);
    float ry = (a0.y + a1.y) + (a2.y + a3.y);
    if (accflag) {
        rx += __builtin_nontemporal_load(&agg[n * 32 + 2 * cp]);
        ry += __builtin_nontemporal_load(&agg[n * 32 + 2 * cp + 1]);
    }
    __builtin_nontemporal_store(rx, &agg[n * 32 + 2 * cp]);
    __builtin_nontemporal_store(ry, &agg[n * 32 + 2 * cp + 1]);
}

// ---------------------------------------------------------------------------
// combine1_transform2 via MFMA: h1 = relu(r1+agg1) [100k x 16];
// t2 = half(h1 @ W2n) [cols 0..31], r2 = h1 @ W2r + b2 [cols 32..63].
// K=16 zero-padded to 32 (quads 2,3 carry zeros). One wave per 16-node tile.
// B-fragments register-resident (loaded once). No LDS in the hot path.
// Fragment layout identical to k_transform1_mfma (HW-validated since R6).
// ---------------------------------------------------------------------------
__global__ __launch_bounds__(256) void k_combine1_transform2_mfma(
    const float* __restrict__ r1, const float* __restrict__ agg1,
    const float* __restrict__ W2n, const float* __restrict__ W2r,
    const float* __restrict__ b2,
    __half* __restrict__ t2, float* __restrict__ r2)
{
    int wave = threadIdx.x >> 6;
    int lane = threadIdx.x & 63;
    int tile = blockIdx.x * 4 + wave;
    if (tile >= N_NODES / 16) return;
    int node0 = tile * 16;
    int m = lane & 15, quad = lane >> 4;

    // B fragments: 4 col groups (0,1 -> W2n cols; 2,3 -> W2r cols)
    half8 bf[4];
#pragma unroll
    for (int g = 0; g < 4; ++g) {
#pragma unroll
        for (int j = 0; j < 8; ++j) {
            int k = quad * 8 + j;
            int c = (g & 1) * 16 + m;
            float w = 0.f;
            if (k < 16) w = (g < 2) ? W2n[k * 32 + c] : W2r[k * 32 + c];
            bf[g][j] = (_Float16)w;
        }
    }

    // A fragment: h1 row m, k = quad*8+j (zeros for k >= 16)
    half8 a;
    if (quad < 2) {
        int idx = (node0 + m) * 16 + quad * 8;
#pragma unroll
        for (int j = 0; j < 8; ++j) {
            float v = r1[idx + j] + agg1[idx + j];
            a[j] = (_Float16)(v > 0.f ? v : 0.f);
        }
    } else {
#pragma unroll
        for (int j = 0; j < 8; ++j) a[j] = (_Float16)0.f;
    }

    float4v accn0 = {0,0,0,0}, accn1 = {0,0,0,0};
    float4v accr0 = {0,0,0,0}, accr1 = {0,0,0,0};
    accn0 = __builtin_amdgcn_mfma_f32_16x16x32_f16(a, bf[0], accn0, 0, 0, 0);
    accn1 = __builtin_amdgcn_mfma_f32_16x16x32_f16(a, bf[1], accn1, 0, 0, 0);
    accr0 = __builtin_amdgcn_mfma_f32_16x16x32_f16(a, bf[2], accr0, 0, 0, 0);
    accr1 = __builtin_amdgcn_mfma_f32_16x16x32_f16(a, bf[3], accr1, 0, 0, 0);

    float bias0 = b2[m], bias1 = b2[16 + m];
#pragma unroll
    for (int reg = 0; reg < 4; ++reg) {
        int node = node0 + quad * 4 + reg;
        t2[node * 32 + m]      = __float2half_rn(accn0[reg]);
        t2[node * 32 + 16 + m] = __float2half_rn(accn1[reg]);
        r2[node * 32 + m]      = accr0[reg] + bias0;
        r2[node * 32 + 16 + m] = accr1[reg] + bias1;
    }
}

// ---------------------------------------------------------------------------
// combine2_transform3 via MFMA: h2 = relu(r2+agg2) [100k x 32];
// t3 = half(h2 @ W3n), r3 = h2 @ W3r + b3. K=32 exactly. One wave per
// 16-node tile; in-place t3/r3 over t2/r2 safe (wave reads its rows first).
// ---------------------------------------------------------------------------
__global__ __launch_bounds__(256) void k_combine2_transform3_mfma(
    const float* __restrict__ r2, const float* __restrict__ agg2,
    const float* __restrict__ W3n, const float* __restrict__ W3r,
    const float* __restrict__ b3,
    __half* __restrict__ t3, float* __restrict__ r3)
{
    int wave = threadIdx.x >> 6;
    int lane = threadIdx.x & 63;
    int tile = blockIdx.x * 4 + wave;
    if (tile >= N_NODES / 16) return;
    int node0 = tile * 16;
    int m = lane & 15, quad = lane >> 4;

    half8 bf[4];
#pragma unroll
    for (int g = 0; g < 4; ++g) {
#pragma unroll
        for (int j = 0; j < 8; ++j) {
            int k = quad * 8 + j;
            int c = (g & 1) * 16 + m;
            bf[g][j] = (_Float16)((g < 2) ? W3n[k * 32 + c] : W3r[k * 32 + c]);
        }
    }

    // A fragment: h2 row m, 8 consecutive channels at quad*8
    half8 a;
    {
        int idx = (node0 + m) * 32 + quad * 8;
#pragma unroll
        for (int j = 0; j < 8; ++j) {
            float v = r2[idx + j] + agg2[idx + j];
            a[j] = (_Float16)(v > 0.f ? v : 0.f);
        }
    }

    float4v accn0 = {0,0,0,0}, accn1 = {0,0,0,0};
    float4v accr0 = {0,0,0,0}, accr1 = {0,0,0,0};
    accn0 = __builtin_amdgcn_mfma_f32_16x16x32_f16(a, bf[0], accn0, 0, 0, 0);
    accn1 = __builtin_amdgcn_mfma_f32_16x16x32_f16(a, bf[1], accn1, 0, 0, 0);
    accr0 = __builtin_amdgcn_mfma_f32_16x16x32_f16(a, bf[2], accr0, 0, 0, 0);
    accr1 = __builtin_amdgcn_mfma_f32_16x16x32_f16(a, bf[3], accr1, 0, 0, 0);

    float bias0 = b3[m], bias1 = b3[16 + m];
#pragma unroll
    for (int reg = 0; reg < 4; ++reg) {
        int node = node0 + quad * 4 + reg;
        t3[node * 32 + m]      = __float2half_rn(accn0[reg]);
        t3[node * 32 + 16 + m] = __float2half_rn(accn1[reg]);
        r3[node * 32 + m]      = accr0[reg] + bias0;
        r3[node * 32 + 16 + m] = accr1[reg] + bias1;
    }
}

// ---------------------------------------------------------------------------
// K7: h3 = relu(r3 + agg32); pooled[batch[n]] += h3[n]
// ---------------------------------------------------------------------------
__global__ __launch_bounds__(256) void k_combine3_pool(
    const float* __restrict__ r3, const float* __restrict__ agg3,
    const int* __restrict__ batch, float* __restrict__ pooled)
{
    int tid = blockIdx.x * 256 + threadIdx.x;
    if (tid >= N_NODES * 32) return;
    int n = tid >> 5, c = tid & 31;
    float v = r3[tid] + agg3[tid];
    v = v > 0.f ? v : 0.f;
    atomicAdd(&pooled[batch[n] * 32 + c], v);
}

// ---------------------------------------------------------------------------
// K8: out = pooled @ Wlin + blin   (1000x32 @ 32x64)
// ---------------------------------------------------------------------------
__global__ __launch_bounds__(64) void k_final(
    const float* __restrict__ pooled, const float* __restrict__ Wlin,
    const float* __restrict__ blin, float* __restrict__ out)
{
    int g = blockIdx.x;
    int o = threadIdx.x;
    float acc = blin[o];
#pragma unroll
    for (int k = 0; k < 32; ++k) acc += pooled[g * 32 + k] * Wlin[k * 64 + o];
    out[g * 64 + o] = acc;
}

static inline char* align16p(char* p) {
    return (char*)(((uintptr_t)p + 15) & ~(uintptr_t)15);
}

extern "C" void kernel_launch(void* const* d_in, const int* in_sizes, int n_in,
                              void* d_out, int out_size, void* d_ws, size_t ws_size,
                              hipStream_t stream) {
    const float* x     = (const float*)d_in[0];
    const int*   ei    = (const int*)d_in[1];
    const int*   batch = (const int*)d_in[2];
    const float* W1r   = (const float*)d_in[3];
    const float* W1n   = (const float*)d_in[4];
    const float* b1    = (const float*)d_in[5];
    const float* W2r   = (const float*)d_in[6];
    const float* W2n   = (const float*)d_in[7];
    const float* b2    = (const float*)d_in[8];
    const float* W3r   = (const float*)d_in[9];
    const float* W3n   = (const float*)d_in[10];
    const float* b3    = (const float*)d_in[11];
    const float* Wlin  = (const float*)d_in[12];
    const float* blin  = (const float*)d_in[13];
    float* out = (float*)d_out;

    // ---- workspace layout (identical to R11) -------------------------------
    char* p = (char*)d_ws;
    int*   cursor = (int*)p;               p += 1024 * 4;
    float* pooled = (float*)p;             p += (size_t)NUM_GRAPHS * 32 * 4;
    int*   rowptr = (int*)p;               p += (size_t)NB2 * RPW * 4;
    p = align16p(p);
    int*   csr    = (int*)p;               p += (size_t)NB2 * CAPB * 4;
    int*   pairbuf= (int*)p;
    __half* t1    = (__half*)pairbuf;                                  // alias
    float*  r1    = (float*)((char*)pairbuf + (size_t)N_NODES * 16 * 2);
    p += (size_t)NB2 * CAPB * 4;
    __half* t2    = (__half*)p;            p += (size_t)N_NODES * 32 * 2;
    float*  r2    = (float*)align16p(p);   p = (char*)r2 + (size_t)N_NODES * 32 * 4;
    float*  agg   = (float*)p;
    __half* t3    = t2;   // in-place
    float*  r3    = r2;   // in-place

    hipMemsetAsync(cursor, 0, (1024 + (size_t)NUM_GRAPHS * 32) * 4, stream);

    // Bucketed CSR build
    k_scatter_pairs<<<NBLK_BIN, 1024, 0, stream>>>(ei, cursor, pairbuf);
    k_build_csr    <<<NB2, 256, 0, stream>>>(cursor, pairbuf, rowptr, csr);

    // Layer pipeline (6250 16-node tiles, 4 waves/block)
    k_transform1_mfma<<<(6250 + 3) / 4, 256, 0, stream>>>(x, W1n, W1r, b1, t1, r1);
    k_gather16b<<<N_NODES * 8 / 256, 256, 0, stream>>>(rowptr, csr,
                    (const __half2*)t1, agg);
    k_combine1_transform2_mfma<<<(6250 + 3) / 4, 256, 0, stream>>>(r1, agg,
                    W2n, W2r, b2, t2, r2);
    k_gather32h<<<N_NODES * 16 / 256, 256, 0, stream>>>(rowptr, csr,
                    (const __half2*)t2, agg, 0, 0);
    k_gather32h<<<N_NODES * 16 / 256, 256, 0, stream>>>(rowptr, csr,
                    (const __half2*)t2, agg, NBH, 1);
    k_combine2_transform3_mfma<<<(6250 + 3) / 4, 256, 0, stream>>>(r2, agg,
                    W3n, W3r, b3, t3, r3);
    k_gather32h<<<N_NODES * 16 / 256, 256, 0, stream>>>(rowptr, csr,
                    (const __half2*)t3, agg, 0, 0);
    k_gather32h<<<N_NODES * 16 / 256, 256, 0, stream>>>(rowptr, csr,
                    (const __half2*)t3, agg, NBH, 1);
    k_combine3_pool<<<N_NODES * 32 / 256, 256, 0, stream>>>(r3, agg, batch, pooled);
    k_final     <<<NUM_GRAPHS, 64, 0, stream>>>(pooled, Wlin, blin, out);
}

// Round 13
// 378.426 us; speedup vs baseline: 1.2905x; 1.1152x over previous
//
#include <hip/hip_runtime.h>
#include <hip/hip_fp16.h>

#define N_NODES   100000
#define N_EDGES   3200000
#define IN_CH     128
#define NUM_GRAPHS 1000
#define NHALF     50000    // src-half boundary
#define NBH       391      // dst-buckets per src-half (256 nodes each)
#define NB2       782      // total buckets = 2 src-halves x 391
#define CAPB      4608     // per-bucket window capacity (mean 4096, +8 sigma)
#define CHUNK     4096     // edges per block in the binning pass
#define NBLK_BIN  782      // ceil(3200000/4096)
#define RPW       257      // rowptr words per bucket (256 nodes + sentinel)
#define NTILE     6250     // N_NODES / 16

typedef __attribute__((ext_vector_type(8))) _Float16 half8;
typedef __attribute__((ext_vector_type(4))) float    float4v;

// ---------------------------------------------------------------------------
// Scatter: LDS counting sort per 4096-edge chunk (R11-proven shape).
// ---------------------------------------------------------------------------
__global__ __launch_bounds__(1024, 2) void k_scatter_pairs(
    const int* __restrict__ ei, int* __restrict__ cursor,
    int* __restrict__ pairbuf)
{
    __shared__ int h[NB2];
    __shared__ int gbase[NB2];
    __shared__ int sstart[NB2 + 1];
    __shared__ int sa[1024];
    __shared__ int sb[1024];
    __shared__ int ebuf[CHUNK];
    __shared__ unsigned short sbk[CHUNK];
    int tid = threadIdx.x;
    if (tid < NB2) h[tid] = 0;
    __syncthreads();
    int base = blockIdx.x * CHUNK;
    int end = min(base + CHUNK, N_EDGES);
    int cntE = end - base;
#pragma unroll
    for (int r = 0; r < 4; ++r) {
        int e = base + tid + 1024 * r;
        if (e < end) {
            int src = ei[e];
            int dst = ei[N_EDGES + e];
            int b = ((src >= NHALF) ? NBH : 0) + (dst >> 8);
            atomicAdd(&h[b], 1);
        }
    }
    __syncthreads();
    sa[tid] = (tid < NB2) ? h[tid] : 0;
    __syncthreads();
    int* A = sa; int* B = sb;
    for (int off = 1; off < 1024; off <<= 1) {
        int v = A[tid] + ((tid >= off) ? A[tid - off] : 0);
        __syncthreads();
        B[tid] = v;
        __syncthreads();
        int* tmp = A; A = B; B = tmp;
    }
    if (tid == 0) sstart[0] = 0;
    if (tid < NB2) sstart[tid + 1] = A[tid];
    __syncthreads();
    if (tid < NB2) {
        int c = sstart[tid + 1] - sstart[tid];
        gbase[tid] = c ? (tid * CAPB + atomicAdd(&cursor[tid], c)) : 0;
        h[tid] = 0;
    }
    __syncthreads();
#pragma unroll
    for (int r = 0; r < 4; ++r) {
        int e = base + tid + 1024 * r;
        if (e < end) {
            int src = ei[e];
            int dst = ei[N_EDGES + e];
            int b = ((src >= NHALF) ? NBH : 0) + (dst >> 8);
            int off = atomicAdd(&h[b], 1);
            int slot = sstart[b] + off;
            ebuf[slot] = src | ((dst & 255) << 17);
            sbk[slot] = (unsigned short)b;
        }
    }
    __syncthreads();
#pragma unroll
    for (int r = 0; r < 4; ++r) {
        int i = tid + 1024 * r;
        if (i < cntE) {
            int b = sbk[i];
            pairbuf[gbase[b] + (i - sstart[b])] = ebuf[i];
        }
    }
}

// ---------------------------------------------------------------------------
// Build CSR: 1024 threads (serial loops 16 -> 4 iters), 2 blocks/CU.
// ---------------------------------------------------------------------------
__global__ __launch_bounds__(1024, 2) void k_build_csr(const int* __restrict__ cursor,
                                                       const int* __restrict__ pairbuf,
                                                       int* __restrict__ rowptr,
                                                       int* __restrict__ csr)
{
    __shared__ int cnt[256];
    __shared__ int scanv[256];
    __shared__ int ebuf[CAPB];
    int b = blockIdx.x;
    int base = b * CAPB;
    int cntE = cursor[b];
    int tid = threadIdx.x;
    if (tid < 256) cnt[tid] = 0;
    __syncthreads();
    for (int i = tid; i < cntE; i += 1024) {
        int p = pairbuf[base + i];
        ebuf[i] = p;
        atomicAdd(&cnt[(p >> 17) & 255], 1);
    }
    __syncthreads();
    int v = 0;
    if (tid < 256) { v = cnt[tid]; scanv[tid] = v; }
    __syncthreads();
    for (int off = 1; off < 256; off <<= 1) {
        int t = (tid < 256 && tid >= off) ? scanv[tid - off] : 0;
        __syncthreads();
        if (tid < 256) scanv[tid] += t;
        __syncthreads();
    }
    if (tid < 256) {
        int ex = scanv[tid] - v;
        rowptr[b * RPW + tid] = base + ex;
        if (tid == 0) rowptr[b * RPW + 256] = base + cntE;
        cnt[tid] = ex;
    }
    __syncthreads();
    for (int i = tid; i < cntE; i += 1024) {
        int p = ebuf[i];
        int pos = atomicAdd(&cnt[(p >> 17) & 255], 1);
        csr[base + pos] = p & 0x1FFFF;
    }
}

// ---------------------------------------------------------------------------
// Graph boundaries from sorted batch: gstart[g] = first node of graph g.
// ---------------------------------------------------------------------------
__global__ __launch_bounds__(256) void k_gstart(const int* __restrict__ batch,
                                                int* __restrict__ gstart)
{
    int n = blockIdx.x * 256 + threadIdx.x;
    if (n >= N_NODES) return;
    int cur = batch[n];
    int prev = (n == 0) ? -1 : batch[n - 1];
    for (int g = prev + 1; g <= cur; ++g) gstart[g] = n;
    if (n == N_NODES - 1)
        for (int g = cur + 1; g <= NUM_GRAPHS; ++g) gstart[g] = N_NODES;
}

// ---------------------------------------------------------------------------
// transform1 via MFMA f16: t1 = half(x @ W1_nbr); r1 = x @ W1_root + b1.
// ---------------------------------------------------------------------------
__global__ __launch_bounds__(256) void k_transform1_mfma(
    const float* __restrict__ x,
    const float* __restrict__ W1n, const float* __restrict__ W1r,
    const float* __restrict__ b1,
    __half* __restrict__ t1, float* __restrict__ r1)
{
    int wave = threadIdx.x >> 6;
    int lane = threadIdx.x & 63;
    int tile = blockIdx.x * 4 + wave;
    int node0 = tile * 16;
    int m = lane & 15, quad = lane >> 4;
    int row = node0 + m;
    if (row >= N_NODES) row = N_NODES - 1;
    const float* xr = x + (size_t)row * IN_CH + quad * 8;

    float4v acc_n = {0.f, 0.f, 0.f, 0.f};
    float4v acc_r = {0.f, 0.f, 0.f, 0.f};
#pragma unroll
    for (int kc = 0; kc < 4; ++kc) {
        half8 a, bn, br;
        const float* xp = xr + kc * 32;
#pragma unroll
        for (int j = 0; j < 8; ++j) a[j] = (_Float16)xp[j];
        int kbase = kc * 32 + quad * 8;
#pragma unroll
        for (int j = 0; j < 8; ++j) {
            bn[j] = (_Float16)W1n[(kbase + j) * 16 + m];
            br[j] = (_Float16)W1r[(kbase + j) * 16 + m];
        }
        acc_n = __builtin_amdgcn_mfma_f32_16x16x32_f16(a, bn, acc_n, 0, 0, 0);
        acc_r = __builtin_amdgcn_mfma_f32_16x16x32_f16(a, br, acc_r, 0, 0, 0);
    }
    float bias = b1[m];
#pragma unroll
    for (int reg = 0; reg < 4; ++reg) {
        int node = node0 + quad * 4 + reg;
        if (node < N_NODES) {
            t1[node * 16 + m] = __float2half_rn(acc_n[reg]);
            r1[node * 16 + m] = acc_r[reg] + bias;
        }
    }
}

// ---------------------------------------------------------------------------
// Layer-1 gather: 16 channels, both src-halves in one pass (t1 = 3.2 MB,
// L2-resident). 8 lanes/node (half2), 8-deep unroll.
// ---------------------------------------------------------------------------
__global__ __launch_bounds__(256) void k_gather16b(
    const int* __restrict__ rowptr, const int* __restrict__ csr,
    const __half2* __restrict__ t, float* __restrict__ agg)
{
    int tid = blockIdx.x * 256 + threadIdx.x;
    int n = tid >> 3, cp = tid & 7;
    float2 a0 = {0.f,0.f}, a1 = {0.f,0.f}, a2 = {0.f,0.f}, a3 = {0.f,0.f};
#pragma unroll
    for (int hh = 0; hh < 2; ++hh) {
        int idx = (hh * NBH + (n >> 8)) * RPW + (n & 255);
        int j = rowptr[idx], end = rowptr[idx + 1];
        for (; j + 7 < end; j += 8) {
            int s0 = __builtin_nontemporal_load(&csr[j]);
            int s1 = __builtin_nontemporal_load(&csr[j + 1]);
            int s2 = __builtin_nontemporal_load(&csr[j + 2]);
            int s3 = __builtin_nontemporal_load(&csr[j + 3]);
            int s4 = __builtin_nontemporal_load(&csr[j + 4]);
            int s5 = __builtin_nontemporal_load(&csr[j + 5]);
            int s6 = __builtin_nontemporal_load(&csr[j + 6]);
            int s7 = __builtin_nontemporal_load(&csr[j + 7]);
            float2 f0 = __half22float2(t[s0 * 8 + cp]);
            float2 f1 = __half22float2(t[s1 * 8 + cp]);
            float2 f2 = __half22float2(t[s2 * 8 + cp]);
            float2 f3 = __half22float2(t[s3 * 8 + cp]);
            float2 f4 = __half22float2(t[s4 * 8 + cp]);
            float2 f5 = __half22float2(t[s5 * 8 + cp]);
            float2 f6 = __half22float2(t[s6 * 8 + cp]);
            float2 f7 = __half22float2(t[s7 * 8 + cp]);
            a0.x += f0.x; a0.y += f0.y;  a1.x += f1.x; a1.y += f1.y;
            a2.x += f2.x; a2.y += f2.y;  a3.x += f3.x; a3.y += f3.y;
            a0.x += f4.x; a0.y += f4.y;  a1.x += f5.x; a1.y += f5.y;
            a2.x += f6.x; a2.y += f6.y;  a3.x += f7.x; a3.y += f7.y;
        }
        for (; j < end; ++j) {
            float2 f = __half22float2(t[__builtin_nontemporal_load(&csr[j]) * 8 + cp]);
            a0.x += f.x; a0.y += f.y;
        }
    }
    float rx = (a0.x + a1.x) + (a2.x + a3.x);
    float ry = (a0.y + a1.y) + (a2.y + a3.y);
    __builtin_nontemporal_store(rx, &agg[n * 16 + 2 * cp]);
    __builtin_nontemporal_store(ry, &agg[n * 16 + 2 * cp + 1]);
}

// ---------------------------------------------------------------------------
// Fused layer-2/3 gather: BOTH src-halves in one launch, 2x grid.
// half = (blockIdx>>2)&1 -> with round-robin blockIdx%8 -> XCD mapping,
// XCDs 0-3 see only t rows [0,50k) (3.2 MB, L2-resident), XCDs 4-7 the rest.
// Each half writes its own agg buffer; combine adds both. 16 lanes/node.
// ---------------------------------------------------------------------------
__global__ __launch_bounds__(256) void k_gather32f(
    const int* __restrict__ rowptr, const int* __restrict__ csr,
    const __half2* __restrict__ t,
    float* __restrict__ aggA, float* __restrict__ aggB)
{
    int b = blockIdx.x;
    int half = (b >> 2) & 1;
    int tile = (b >> 3) * 4 + (b & 3);
    if (tile >= NTILE) return;
    int n = tile * 16 + (threadIdx.x >> 4);
    int cp = threadIdx.x & 15;
    float* agg = half ? aggB : aggA;
    int idx = (half * NBH + (n >> 8)) * RPW + (n & 255);
    int j = rowptr[idx], end = rowptr[idx + 1];
    float2 a0 = {0.f,0.f}, a1 = {0.f,0.f}, a2 = {0.f,0.f}, a3 = {0.f,0.f};
    for (; j + 7 < end; j += 8) {
        int s0 = __builtin_nontemporal_load(&csr[j]);
        int s1 = __builtin_nontemporal_load(&csr[j + 1]);
        int s2 = __builtin_nontemporal_load(&csr[j + 2]);
        int s3 = __builtin_nontemporal_load(&csr[j + 3]);
        int s4 = __builtin_nontemporal_load(&csr[j + 4]);
        int s5 = __builtin_nontemporal_load(&csr[j + 5]);
        int s6 = __builtin_nontemporal_load(&csr[j + 6]);
        int s7 = __builtin_nontemporal_load(&csr[j + 7]);
        float2 f0 = __half22float2(t[s0 * 16 + cp]);
        float2 f1 = __half22float2(t[s1 * 16 + cp]);
        float2 f2 = __half22float2(t[s2 * 16 + cp]);
        float2 f3 = __half22float2(t[s3 * 16 + cp]);
        float2 f4 = __half22float2(t[s4 * 16 + cp]);
        float2 f5 = __half22float2(t[s5 * 16 + cp]);
        float2 f6 = __half22float2(t[s6 * 16 + cp]);
        float2 f7 = __half22float2(t[s7 * 16 + cp]);
        a0.x += f0.x; a0.y += f0.y;  a1.x += f1.x; a1.y += f1.y;
        a2.x += f2.x; a2.y += f2.y;  a3.x += f3.x; a3.y += f3.y;
        a0.x += f4.x; a0.y += f4.y;  a1.x += f5.x; a1.y += f5.y;
        a2.x += f6.x; a2.y += f6.y;  a3.x += f7.x; a3.y += f7.y;
    }
    for (; j < end; ++j) {
        float2 f = __half22float2(t[__builtin_nontemporal_load(&csr[j]) * 16 + cp]);
        a0.x += f.x; a0.y += f.y;
    }
    float rx = (a0.x + a1.x) + (a2.x + a3.x);
    float ry = (a0.y + a1.y) + (a2.y + a3.y);
    __builtin_nontemporal_store(rx, &agg[n * 32 + 2 * cp]);
    __builtin_nontemporal_store(ry, &agg[n * 32 + 2 * cp + 1]);
}

// ---------------------------------------------------------------------------
// combine1_transform2 via MFMA: h1 = relu(r1+agg1) [K=16 padded to 32].
// ---------------------------------------------------------------------------
__global__ __launch_bounds__(256) void k_combine1_transform2_mfma(
    const float* __restrict__ r1, const float* __restrict__ agg1,
    const float* __restrict__ W2n, const float* __restrict__ W2r,
    const float* __restrict__ b2,
    __half* __restrict__ t2, float* __restrict__ r2)
{
    int wave = threadIdx.x >> 6;
    int lane = threadIdx.x & 63;
    int tile = blockIdx.x * 4 + wave;
    if (tile >= NTILE) return;
    int node0 = tile * 16;
    int m = lane & 15, quad = lane >> 4;

    half8 bf[4];
#pragma unroll
    for (int g = 0; g < 4; ++g) {
#pragma unroll
        for (int j = 0; j < 8; ++j) {
            int k = quad * 8 + j;
            int c = (g & 1) * 16 + m;
            float w = 0.f;
            if (k < 16) w = (g < 2) ? W2n[k * 32 + c] : W2r[k * 32 + c];
            bf[g][j] = (_Float16)w;
        }
    }

    half8 a;
    if (quad < 2) {
        int idx = (node0 + m) * 16 + quad * 8;
#pragma unroll
        for (int j = 0; j < 8; ++j) {
            float v = r1[idx + j] + agg1[idx + j];
            a[j] = (_Float16)(v > 0.f ? v : 0.f);
        }
    } else {
#pragma unroll
        for (int j = 0; j < 8; ++j) a[j] = (_Float16)0.f;
    }

    float4v accn0 = {0,0,0,0}, accn1 = {0,0,0,0};
    float4v accr0 = {0,0,0,0}, accr1 = {0,0,0,0};
    accn0 = __builtin_amdgcn_mfma_f32_16x16x32_f16(a, bf[0], accn0, 0, 0, 0);
    accn1 = __builtin_amdgcn_mfma_f32_16x16x32_f16(a, bf[1], accn1, 0, 0, 0);
    accr0 = __builtin_amdgcn_mfma_f32_16x16x32_f16(a, bf[2], accr0, 0, 0, 0);
    accr1 = __builtin_amdgcn_mfma_f32_16x16x32_f16(a, bf[3], accr1, 0, 0, 0);

    float bias0 = b2[m], bias1 = b2[16 + m];
#pragma unroll
    for (int reg = 0; reg < 4; ++reg) {
        int node = node0 + quad * 4 + reg;
        t2[node * 32 + m]      = __float2half_rn(accn0[reg]);
        t2[node * 32 + 16 + m] = __float2half_rn(accn1[reg]);
        r2[node * 32 + m]      = accr0[reg] + bias0;
        r2[node * 32 + 16 + m] = accr1[reg] + bias1;
    }
}

// ---------------------------------------------------------------------------
// combine2_transform3 via MFMA: h2 = relu(r2 + aggA + aggB) [K=32].
// ---------------------------------------------------------------------------
__global__ __launch_bounds__(256) void k_combine2_transform3_mfma(
    const float* __restrict__ r2,
    const float* __restrict__ aggA, const float* __restrict__ aggB,
    const float* __restrict__ W3n, const float* __restrict__ W3r,
    const float* __restrict__ b3,
    __half* __restrict__ t3, float* __restrict__ r3)
{
    int wave = threadIdx.x >> 6;
    int lane = threadIdx.x & 63;
    int tile = blockIdx.x * 4 + wave;
    if (tile >= NTILE) return;
    int node0 = tile * 16;
    int m = lane & 15, quad = lane >> 4;

    half8 bf[4];
#pragma unroll
    for (int g = 0; g < 4; ++g) {
#pragma unroll
        for (int j = 0; j < 8; ++j) {
            int k = quad * 8 + j;
            int c = (g & 1) * 16 + m;
            bf[g][j] = (_Float16)((g < 2) ? W3n[k * 32 + c] : W3r[k * 32 + c]);
        }
    }

    half8 a;
    {
        int idx = (node0 + m) * 32 + quad * 8;
#pragma unroll
        for (int j = 0; j < 8; ++j) {
            float v = r2[idx + j] + aggA[idx + j] + aggB[idx + j];
            a[j] = (_Float16)(v > 0.f ? v : 0.f);
        }
    }

    float4v accn0 = {0,0,0,0}, accn1 = {0,0,0,0};
    float4v accr0 = {0,0,0,0}, accr1 = {0,0,0,0};
    accn0 = __builtin_amdgcn_mfma_f32_16x16x32_f16(a, bf[0], accn0, 0, 0, 0);
    accn1 = __builtin_amdgcn_mfma_f32_16x16x32_f16(a, bf[1], accn1, 0, 0, 0);
    accr0 = __builtin_amdgcn_mfma_f32_16x16x32_f16(a, bf[2], accr0, 0, 0, 0);
    accr1 = __builtin_amdgcn_mfma_f32_16x16x32_f16(a, bf[3], accr1, 0, 0, 0);

    float bias0 = b3[m], bias1 = b3[16 + m];
#pragma unroll
    for (int reg = 0; reg < 4; ++reg) {
        int node = node0 + quad * 4 + reg;
        t3[node * 32 + m]      = __float2half_rn(accn0[reg]);
        t3[node * 32 + 16 + m] = __float2half_rn(accn1[reg]);
        r3[node * 32 + m]      = accr0[reg] + bias0;
        r3[node * 32 + 16 + m] = accr1[reg] + bias1;
    }
}

// ---------------------------------------------------------------------------
// Fused combine3 + pool + final: one block per graph (batch sorted ->
// contiguous node range). h3 = relu(r3+aggA+aggB); pooled = sum; out =
// pooled @ Wlin + blin. No atomics, no pooled global buffer.
// ---------------------------------------------------------------------------
__global__ __launch_bounds__(256) void k_pool_final(
    const float* __restrict__ r3,
    const float* __restrict__ aggA, const float* __restrict__ aggB,
    const int* __restrict__ gstart,
    const float* __restrict__ Wlin, const float* __restrict__ blin,
    float* __restrict__ out)
{
    __shared__ float part[8][32];
    __shared__ float pooled[32];
    int g = blockIdx.x;
    int s = gstart[g], e = gstart[g + 1];
    int nl = threadIdx.x >> 5, c = threadIdx.x & 31;
    float acc = 0.f;
    for (int n = s + nl; n < e; n += 8) {
        int idx = n * 32 + c;
        float v = r3[idx] + aggA[idx] + aggB[idx];
        acc += v > 0.f ? v : 0.f;
    }
    part[nl][c] = acc;
    __syncthreads();
    if (threadIdx.x < 32) {
        float s2 = 0.f;
#pragma unroll
        for (int i = 0; i < 8; ++i) s2 += part[i][threadIdx.x];
        pooled[threadIdx.x] = s2;
    }
    __syncthreads();
    if (threadIdx.x < 64) {
        int o = threadIdx.x;
        float a = blin[o];
#pragma unroll
        for (int k = 0; k < 32; ++k) a += pooled[k] * Wlin[k * 64 + o];
        out[g * 64 + o] = a;
    }
}

static inline char* align16p(char* p) {
    return (char*)(((uintptr_t)p + 15) & ~(uintptr_t)15);
}

extern "C" void kernel_launch(void* const* d_in, const int* in_sizes, int n_in,
                              void* d_out, int out_size, void* d_ws, size_t ws_size,
                              hipStream_t stream) {
    const float* x     = (const float*)d_in[0];
    const int*   ei    = (const int*)d_in[1];
    const int*   batch = (const int*)d_in[2];
    const float* W1r   = (const float*)d_in[3];
    const float* W1n   = (const float*)d_in[4];
    const float* b1    = (const float*)d_in[5];
    const float* W2r   = (const float*)d_in[6];
    const float* W2n   = (const float*)d_in[7];
    const float* b2    = (const float*)d_in[8];
    const float* W3r   = (const float*)d_in[9];
    const float* W3n   = (const float*)d_in[10];
    const float* b3    = (const float*)d_in[11];
    const float* Wlin  = (const float*)d_in[12];
    const float* blin  = (const float*)d_in[13];
    float* out = (float*)d_out;

    // ---- workspace layout --------------------------------------------------
    // cursor[1024] | gstart[1024] | rowptr[782*257] | csr[14.4MB] |
    // pairbuf[14.4MB, aliases t1(3.2)+r1(6.4)] | t2 6.4MB | r2 12.8MB |
    // aggA 12.8MB | aggB 12.8MB.  ~75 MB.
    char* p = (char*)d_ws;
    int*   cursor = (int*)p;               p += 1024 * 4;
    int*   gstart = (int*)p;               p += 1024 * 4;
    int*   rowptr = (int*)p;               p += (size_t)NB2 * RPW * 4;
    p = align16p(p);
    int*   csr    = (int*)p;               p += (size_t)NB2 * CAPB * 4;
    int*   pairbuf= (int*)p;
    __half* t1    = (__half*)pairbuf;                                  // alias
    float*  r1    = (float*)((char*)pairbuf + (size_t)N_NODES * 16 * 2);
    p += (size_t)NB2 * CAPB * 4;
    __half* t2    = (__half*)p;            p += (size_t)N_NODES * 32 * 2;
    float*  r2    = (float*)align16p(p);   p = (char*)r2 + (size_t)N_NODES * 32 * 4;
    float*  aggA  = (float*)p;             p += (size_t)N_NODES * 32 * 4;
    float*  aggB  = (float*)p;
    __half* t3    = t2;   // in-place
    float*  r3    = r2;   // in-place

    hipMemsetAsync(cursor, 0, 1024 * 4, stream);

    // Bucketed CSR build + graph boundaries
    k_scatter_pairs<<<NBLK_BIN, 1024, 0, stream>>>(ei, cursor, pairbuf);
    k_build_csr    <<<NB2, 1024, 0, stream>>>(cursor, pairbuf, rowptr, csr);
    k_gstart       <<<(N_NODES + 255) / 256, 256, 0, stream>>>(batch, gstart);

    // Layer pipeline
    k_transform1_mfma<<<(NTILE + 3) / 4, 256, 0, stream>>>(x, W1n, W1r, b1, t1, r1);
    k_gather16b<<<N_NODES * 8 / 256, 256, 0, stream>>>(rowptr, csr,
                    (const __half2*)t1, aggA);
    k_combine1_transform2_mfma<<<(NTILE + 3) / 4, 256, 0, stream>>>(r1, aggA,
                    W2n, W2r, b2, t2, r2);
    k_gather32f<<<1563 * 8, 256, 0, stream>>>(rowptr, csr,
                    (const __half2*)t2, aggA, aggB);
    k_combine2_transform3_mfma<<<(NTILE + 3) / 4, 256, 0, stream>>>(r2, aggA, aggB,
                    W3n, W3r, b3, t3, r3);
    k_gather32f<<<1563 * 8, 256, 0, stream>>>(rowptr, csr,
                    (const __half2*)t3, aggA, aggB);
    k_pool_final<<<NUM_GRAPHS, 256, 0, stream>>>(r3, aggA, aggB, gstart,
                    Wlin, blin, out);
}